// Round 9
// baseline (118.020 us; speedup 1.0000x reference)
//
#include <hip/hip_runtime.h>

typedef __attribute__((ext_vector_type(8))) short short8;
typedef __attribute__((ext_vector_type(4))) float f32x4;

#define DEVI __device__ __forceinline__

static constexpr int HIDDEN   = 2048;
static constexpr int NHEADS   = 16;
static constexpr int NKV      = 8;
static constexpr int HDIM     = 128;
static constexpr int QLEN     = 2048;
static constexpr int KVLEN    = 4096;
static constexpr int ENCLEN   = 512;
static constexpr int NREQ     = 8;
static constexpr float SCALING = 0.0625f;   // 256^-0.5
static constexpr float EPS     = 1e-6f;

DEVI unsigned short f2bf(float f) {
  unsigned int b = __float_as_uint(f);
  b += 0x7FFFu + ((b >> 16) & 1u);          // RNE
  return (unsigned short)(b >> 16);
}

DEVI void g2l16(const void* g, void* l) {
  __builtin_amdgcn_global_load_lds(
      (const __attribute__((address_space(1))) void*)g,
      (__attribute__((address_space(3))) void*)l, 16, 0, 0);
}

// ---------------- fused fp32 -> bf16 convert of all three inputs ----------------
__global__ __launch_bounds__(256) void cvt_all(const float* __restrict__ h,
                                               const float* __restrict__ e,
                                               const float* __restrict__ w,
                                               unsigned short* __restrict__ hb,
                                               unsigned short* __restrict__ eb,
                                               unsigned short* __restrict__ wb) {
  constexpr long S1 = (long)2048 * 2048, S2 = (long)4096 * 2048;
  long i = ((long)blockIdx.x * 256 + threadIdx.x) * 8;
  const float* src;
  unsigned short* dst;
  if (i < S1)           { src = h + i;            dst = hb + i; }
  else if (i < S1 + S2) { src = e + (i - S1);     dst = eb + (i - S1); }
  else                  { src = w + (i - S1 - S2); dst = wb + (i - S1 - S2); }
  float4 a = *(const float4*)src;
  float4 b = *(const float4*)(src + 4);
  short8 o;
  o[0] = (short)f2bf(a.x); o[1] = (short)f2bf(a.y);
  o[2] = (short)f2bf(a.z); o[3] = (short)f2bf(a.w);
  o[4] = (short)f2bf(b.x); o[5] = (short)f2bf(b.y);
  o[6] = (short)f2bf(b.z); o[7] = (short)f2bf(b.w);
  *(short8*)dst = o;
}

// ================= 128x128 GEMM: 768 blocks = exactly 3/CU =================
// 4 waves (2x2), wave tile 64x64, BK=32, ring-3 LDS (3 x 16KB = 48KB).
// 3 unsynchronized blocks per CU overlap each other's DS and MFMA phases.
// Per subtile per wave: 8 ds_read_b128 + 16 MFMA; staging = 4 gloads/block.
// Ring: stage t+2 into slot (t+2)%3 (= slot read at t-1, safe after barrier);
// vmcnt(4) at top leaves newest group outstanding -> slot t landed.
// N-span 128 = exactly one head -> block-local RMS-norm / transpose epilogue.

#define SBAR  __builtin_amdgcn_s_barrier()

DEVI short8 rdfrag(const char* unit, int row, int lg) {
  int L = row >> 1;
  int g = ((row & 1) << 2) + lg;
  return *(const short8*)(unit + L * 128 + ((g ^ (L & 7)) << 4));
}

__global__ __launch_bounds__(256, 3) void gemm_qkv8(
    const unsigned short* __restrict__ Adec, const unsigned short* __restrict__ Aenc,
    const unsigned short* __restrict__ Bw,
    const float* __restrict__ q_nw, const float* __restrict__ k_nw,
    unsigned short* __restrict__ q_bf, unsigned short* __restrict__ k_bf,
    unsigned short* __restrict__ v_t) {
  extern __shared__ char lds[];
  const int K = 2048, NST = 64;   // 64 subtiles of K=32

  // XCD swizzle over 768 = 8*96; bx-major so each XCD keeps 2 B-panels hot
  int flat = blockIdx.x;
  int swz = (flat & 7) * 96 + (flat >> 3);
  int bx = swz / 48, byy = swz % 48;        // bx: N-tile (= head), byy: M-tile

  const unsigned short* A;
  int bm0;
  if (byy < 16) { A = Adec; bm0 = byy * 128; }
  else          { A = Aenc; bm0 = (byy - 16) * 128; }
  const unsigned short* Bp = Bw + (byy < 16 ? 0 : (size_t)2048 * 2048);
  const int bn0 = bx * 128;

  const int tid = threadIdx.x, lane = tid & 63, wave = tid >> 6;
  const int lr = lane & 15, lg = lane >> 4;
  const int wr = wave >> 1, wc = wave & 1;   // 2M x 2N

  // stage source mapping for the 2 gload insts per unit (linear dest chunk ->
  // swizzled source row/col)
  int srow[2], scol[2];
#pragma unroll
  for (int i = 0; i < 2; ++i) {
    int sB = (i * 256 + tid) * 16;
    int sL = sB >> 7, sgp = (sB >> 4) & 7;
    int sg = sgp ^ (sL & 7);
    srow[i] = sL * 2 + (sg >> 2);
    scol[i] = (sg & 3) * 8;
  }
  const size_t aoff0 = (size_t)(bm0 + srow[0]) * K + scol[0];
  const size_t aoff1 = (size_t)(bm0 + srow[1]) * K + scol[1];
  const size_t boff0 = (size_t)(bn0 + srow[0]) * K + scol[0];
  const size_t boff1 = (size_t)(bn0 + srow[1]) * K + scol[1];
  const int dB = tid * 16;

#define STG4(t)                                                       \
  {                                                                   \
    const size_t kc = (size_t)(t) * 32;                               \
    char* base = lds + ((t) % 3) * 16384;                             \
    g2l16(A + aoff0 + kc,  base + dB);                                \
    g2l16(A + aoff1 + kc,  base + 4096 + dB);                         \
    g2l16(Bp + boff0 + kc, base + 8192 + dB);                         \
    g2l16(Bp + boff1 + kc, base + 12288 + dB);                        \
  }

  f32x4 acc[4][4] = {};

#define MM16(aS, bS)                                                  \
  {                                                                   \
    __builtin_amdgcn_s_setprio(1);                                    \
    _Pragma("unroll") for (int m = 0; m < 4; ++m)                     \
        _Pragma("unroll") for (int n = 0; n < 4; ++n)                 \
            acc[m][n] = __builtin_amdgcn_mfma_f32_16x16x32_bf16(      \
                aS[m], bS[n], acc[m][n], 0, 0, 0);                    \
    __builtin_amdgcn_s_setprio(0);                                    \
  }

  // ---- prologue: stage subtiles 0,1 ----
  STG4(0); STG4(1);

#pragma unroll 3
  for (int t = 0; t < NST - 1; ++t) {
    asm volatile("s_waitcnt vmcnt(4)" ::: "memory");
    SBAR;
    const char* ua = lds + (t % 3) * 16384;
    const char* ub = ua + 8192;
    short8 a[4], b[4];
#pragma unroll
    for (int m = 0; m < 4; ++m) a[m] = rdfrag(ua, wr * 64 + m * 16 + lr, lg);
#pragma unroll
    for (int n = 0; n < 4; ++n) b[n] = rdfrag(ub, wc * 64 + n * 16 + lr, lg);
    if (t < NST - 2) STG4(t + 2);
    MM16(a, b);
  }
  {  // t = 63: drain
    asm volatile("s_waitcnt vmcnt(0)" ::: "memory");
    SBAR;
    const char* ua = lds + ((NST - 1) % 3) * 16384;
    const char* ub = ua + 8192;
    short8 a[4], b[4];
#pragma unroll
    for (int m = 0; m < 4; ++m) a[m] = rdfrag(ua, wr * 64 + m * 16 + lr, lg);
#pragma unroll
    for (int n = 0; n < 4; ++n) b[n] = rdfrag(ub, wc * 64 + n * 16 + lr, lg);
    MM16(a, b);
  }

  // ================= fused epilogue: one head per block =================
  // tile row = wr*64 + m*16 + lg*4 + r (token), col = wc*64 + n*16 + lr (dim)
  const int btype = (byy < 16) ? 0 : (bx < 8 ? 1 : 2);  // 0=Q,1=K,2=V

  if (btype < 2) {
    float* Lf = (float*)lds;                 // [64][132] f32 = 33.8KB
    const float* wnorm = (btype == 0) ? q_nw : k_nw;
    const float fscale = (btype == 0) ? SCALING : 1.0f;
    unsigned short* dst = (btype == 0) ? q_bf : k_bf;
    const size_t LEN = (btype == 0) ? (size_t)QLEN : (size_t)KVLEN;
    const int g16 = tid >> 4, l16 = tid & 15;
    const int dloc = l16 * 8;
    float wv[8];
#pragma unroll
    for (int j = 0; j < 8; ++j) wv[j] = 1.0f + wnorm[dloc + j];

#pragma unroll
    for (int hh = 0; hh < 2; ++hh) {
      SBAR;
      if (wr == hh) {
#pragma unroll
        for (int m = 0; m < 4; ++m)
#pragma unroll
          for (int n = 0; n < 4; ++n)
#pragma unroll
            for (int r = 0; r < 4; ++r)
              Lf[(m * 16 + lg * 4 + r) * 132 + wc * 64 + n * 16 + lr] =
                  acc[m][n][r];
      }
      SBAR;
#pragma unroll
      for (int it = 0; it < 4; ++it) {
        int row = it * 16 + g16;
        const float* src = &Lf[row * 132 + dloc];
        f32x4 x0 = *(const f32x4*)src;
        f32x4 x1 = *(const f32x4*)(src + 4);
        float ssq = x0[0]*x0[0] + x0[1]*x0[1] + x0[2]*x0[2] + x0[3]*x0[3] +
                    x1[0]*x1[0] + x1[1]*x1[1] + x1[2]*x1[2] + x1[3]*x1[3];
#pragma unroll
        for (int msk = 8; msk >= 1; msk >>= 1) ssq += __shfl_xor(ssq, msk);
        float sc = rsqrtf(ssq * (1.0f / 128.0f) + EPS) * fscale;
        short8 o;
        o[0] = (short)f2bf(x0[0] * sc * wv[0]); o[1] = (short)f2bf(x0[1] * sc * wv[1]);
        o[2] = (short)f2bf(x0[2] * sc * wv[2]); o[3] = (short)f2bf(x0[3] * sc * wv[3]);
        o[4] = (short)f2bf(x1[0] * sc * wv[4]); o[5] = (short)f2bf(x1[1] * sc * wv[5]);
        o[6] = (short)f2bf(x1[2] * sc * wv[6]); o[7] = (short)f2bf(x1[3] * sc * wv[7]);
        int tok = bm0 + hh * 64 + row;
        *(short8*)&dst[((size_t)bx * LEN + tok) * 128 + dloc] = o;
      }
    }
  } else {
    float* Lv = (float*)lds;                 // [128 d][66] f32 = 33.8KB
    const int kh = bx - 8;
#pragma unroll
    for (int hh = 0; hh < 2; ++hh) {
      SBAR;
      if (wr == hh) {
#pragma unroll
        for (int m = 0; m < 4; ++m)
#pragma unroll
          for (int n = 0; n < 4; ++n)
            *(f32x4*)&Lv[(wc * 64 + n * 16 + lr) * 66 + m * 16 + lg * 4] =
                acc[m][n];
      }
      SBAR;
      int d = tid >> 1, th = tid & 1;        // d 0..127, token half of 32
      const float* src = &Lv[d * 66 + th * 32];
      int tok0 = bm0 + hh * 64 + th * 32;
      unsigned short* vp = &v_t[((size_t)kh * 128 + d) * KVLEN + tok0];
#pragma unroll
      for (int j = 0; j < 4; ++j) {
        f32x4 v0 = *(const f32x4*)(src + j * 8);
        f32x4 v1 = *(const f32x4*)(src + j * 8 + 4);
        short8 o;
        o[0] = (short)f2bf(v0[0]); o[1] = (short)f2bf(v0[1]);
        o[2] = (short)f2bf(v0[2]); o[3] = (short)f2bf(v0[3]);
        o[4] = (short)f2bf(v1[0]); o[5] = (short)f2bf(v1[1]);
        o[6] = (short)f2bf(v1[2]); o[7] = (short)f2bf(v1[3]);
        *(short8*)(vp + j * 8) = o;
      }
    }
  }
#undef STG4
#undef MM16
}

// ---------------- attention: K/V chunk double-buffer, 1 barrier/chunk ----------------
// grid (32 qtiles, 16 heads); block 256 = 4 waves x 16 q-rows; 8 KV chunks of 64.
// smem: Ks[2] @0 (2x16KB), Vs[2] @32768 (2x16KB), Ps @65536 (8KB) = 72KB.
__global__ __launch_bounds__(256, 4) void attn_kernel(
    const unsigned short* __restrict__ qb,   // [16][2048][128]
    const unsigned short* __restrict__ kb,   // [8][4096][128]
    const unsigned short* __restrict__ vt,   // [8][128][4096]
    const int* __restrict__ seq_lens,
    float* __restrict__ out) {               // [2048][2048]
  __shared__ __align__(16) char smem[73728];

  const int h = blockIdx.y;
  const int t0 = blockIdx.x * 64;
  int req = 0, qs = 0;
#pragma unroll 1
  while (req < NREQ - 1 && qs + seq_lens[req] <= t0) { qs += seq_lens[req]; ++req; }
  const int slen = seq_lens[req];
  const int rows = min(64, qs + slen - t0);
  if (rows <= 0) return;
  const int qbase = t0;

  const int tid = threadIdx.x, lane = tid & 63, wave = tid >> 6;
  const int lr = lane & 15, lg = lane >> 4;
  const int m0w = wave * 16;
  const int kh = h >> 1;
  const int kv0 = req * ENCLEN;

#define STAGE_K(c, db)                                                        \
  _Pragma("unroll") for (int i = 0; i < 4; ++i) {                             \
    int idx = i * 256 + tid;                                                  \
    int row = idx >> 4, slot = idx & 15;                                      \
    g2l16(kb + ((size_t)kh * KVLEN + kv0 + (c) * 64 + row) * 128 +            \
              ((slot ^ (row & 15)) << 3),                                     \
          smem + (db) * 16384 + idx * 16);                                    \
  }
#define STAGE_V(c, db)                                                        \
  _Pragma("unroll") for (int i = 0; i < 4; ++i) {                             \
    int idx = i * 256 + tid;                                                  \
    int row = idx >> 3, slot = idx & 7;                                       \
    g2l16(vt + ((size_t)kh * 128 + row) * KVLEN + kv0 + (c) * 64 +            \
              ((slot ^ (row & 7)) << 3),                                      \
          smem + 32768 + (db) * 16384 + idx * 16);                            \
  }

  unsigned short* Ps = (unsigned short*)(smem + 65536);

  short8 a_q[4];
  {
    int qr = qbase + min(m0w + lr, rows - 1);
    const unsigned short* qp = qb + ((size_t)h * QLEN + qr) * 128 + lg * 8;
#pragma unroll
    for (int ks = 0; ks < 4; ++ks) a_q[ks] = *(const short8*)(qp + ks * 32);
  }

  f32x4 acc[8] = {};
  float mrow[4], lsum[4];
#pragma unroll
  for (int r = 0; r < 4; ++r) { mrow[r] = -1e30f; lsum[r] = 0.f; }

  // prologue: stage chunk 0 into buffer 0
  STAGE_K(0, 0); STAGE_V(0, 0);

  int cb = 0;
#pragma unroll 1
  for (int c = 0; c < 8; ++c) {
    asm volatile("s_waitcnt vmcnt(0)" ::: "memory");
    __syncthreads();
    if (c < 7) { STAGE_K(c + 1, cb ^ 1); STAGE_V(c + 1, cb ^ 1); }
    const unsigned short* Kb = (const unsigned short*)(smem + cb * 16384);
    const unsigned short* Vb = (const unsigned short*)(smem + 32768 + cb * 16384);

    f32x4 s[4] = {};
#pragma unroll
    for (int ks = 0; ks < 4; ++ks) {
      short8 bk[4];
#pragma unroll
      for (int n = 0; n < 4; ++n) {
        int row = n * 16 + lr;
        bk[n] = *(const short8*)&Kb[row * 128 + (((ks * 4 + lg) ^ (row & 15)) << 3)];
      }
#pragma unroll
      for (int n = 0; n < 4; ++n)
        s[n] = __builtin_amdgcn_mfma_f32_16x16x32_bf16(a_q[ks], bk[n], s[n], 0, 0, 0);
    }

#pragma unroll
    for (int r = 0; r < 4; ++r) {
      float mx = fmaxf(fmaxf(s[0][r], s[1][r]), fmaxf(s[2][r], s[3][r]));
#pragma unroll
      for (int msk = 8; msk >= 1; msk >>= 1) mx = fmaxf(mx, __shfl_xor(mx, msk));
      float mnew = fmaxf(mrow[r], mx);
      float al = __expf(mrow[r] - mnew);
      mrow[r] = mnew;
      float rs = 0.f;
#pragma unroll
      for (int n = 0; n < 4; ++n) {
        float p = __expf(s[n][r] - mnew);
        s[n][r] = p;
        rs += p;
      }
#pragma unroll
      for (int msk = 8; msk >= 1; msk >>= 1) rs += __shfl_xor(rs, msk);
      lsum[r] = lsum[r] * al + rs;
#pragma unroll
      for (int n2 = 0; n2 < 8; ++n2) acc[n2][r] *= al;
    }

#pragma unroll
    for (int n = 0; n < 4; ++n)
#pragma unroll
      for (int r = 0; r < 4; ++r) {
        int row = m0w + lg * 4 + r;
        int col = n * 16 + lr;
        Ps[row * 64 + (col ^ ((row & 7) << 3))] = f2bf(s[n][r]);
      }
    asm volatile("s_waitcnt lgkmcnt(0)" ::: "memory");
    __builtin_amdgcn_sched_barrier(0);

#pragma unroll
    for (int ks = 0; ks < 2; ++ks) {
      int prow = m0w + lr;
      short8 pa = *(const short8*)&Ps[prow * 64 + (((ks * 4 + lg) ^ (prow & 7)) << 3)];
#pragma unroll
      for (int n2 = 0; n2 < 8; ++n2) {
        int row = n2 * 16 + lr;
        short8 bv = *(const short8*)&Vb[row * 64 + (((ks * 4 + lg) ^ (row & 7)) << 3)];
        acc[n2] = __builtin_amdgcn_mfma_f32_16x16x32_bf16(pa, bv, acc[n2], 0, 0, 0);
      }
    }
    cb ^= 1;
  }
  __syncthreads();

  // normalize in-register, restage via LDS, store fp32 out directly
  float inv[4];
#pragma unroll
  for (int r = 0; r < 4; ++r) inv[r] = 1.0f / lsum[r];
#pragma unroll
  for (int n2 = 0; n2 < 8; ++n2)
#pragma unroll
    for (int r = 0; r < 4; ++r) acc[n2][r] *= inv[r];

  constexpr int OFS = 132;
  float* Of = (float*)smem;                  // 64*132*4 = 33.8KB
#pragma unroll
  for (int n2 = 0; n2 < 8; ++n2)
#pragma unroll
    for (int r = 0; r < 4; ++r)
      Of[(m0w + lg * 4 + r) * OFS + n2 * 16 + lr] = acc[n2][r];
  __syncthreads();
#pragma unroll
  for (int p = 0; p < 8; ++p) {
    int idx = p * 256 + tid;
    int row = idx >> 5, c4 = (idx & 31) * 4;
    if (row < rows) {
      f32x4 v = *(const f32x4*)&Of[row * OFS + c4];
      *(f32x4*)&out[(size_t)(qbase + row) * 2048 + h * 128 + c4] = v;
    }
  }
#undef STAGE_K
#undef STAGE_V
}

// ---------------- launch ----------------
extern "C" void kernel_launch(void* const* d_in, const int* in_sizes, int n_in,
                              void* d_out, int out_size, void* d_ws, size_t ws_size,
                              hipStream_t stream) {
  const float* hidden = (const float*)d_in[0];
  const float* enc    = (const float*)d_in[1];
  const float* w_qkv  = (const float*)d_in[2];
  const float* q_nw   = (const float*)d_in[3];
  const float* k_nw   = (const float*)d_in[4];
  const int*   slens  = (const int*)d_in[5];
  float* out = (float*)d_out;

  char* ws = (char*)d_ws;
  unsigned short* h_bf = (unsigned short*)(ws + 0);           //  8.39 MB
  unsigned short* e_bf = (unsigned short*)(ws + 8388608);     // 16.78 MB
  unsigned short* w_bf = (unsigned short*)(ws + 25165824);    // 16.78 MB
  unsigned short* q_bf = (unsigned short*)(ws + 41943040);    //  8.39 MB
  unsigned short* k_bf = (unsigned short*)(ws + 50331648);    //  8.39 MB
  unsigned short* v_t  = (unsigned short*)(ws + 58720256);    //  8.39 MB (ends 67.1MB)

  static bool attr_set = false;
  if (!attr_set) {
    hipFuncSetAttribute((const void*)gemm_qkv8,
                        hipFuncAttributeMaxDynamicSharedMemorySize, 49152);
    attr_set = true;
  }

  cvt_all<<<10240, 256, 0, stream>>>(hidden, enc, w_qkv, h_bf, e_bf, w_bf);

  gemm_qkv8<<<768, 256, 49152, stream>>>(h_bf, e_bf, w_bf, q_nw, k_nw,
                                         q_bf, k_bf, v_t);

  attn_kernel<<<dim3(32, 16), 256, 0, stream>>>(q_bf, k_bf, v_t, slens, out);
}

// Round 10
// 114.259 us; speedup vs baseline: 1.0329x; 1.0329x over previous
//
#include <hip/hip_runtime.h>

typedef __attribute__((ext_vector_type(8))) short short8;
typedef __attribute__((ext_vector_type(4))) float f32x4;

#define DEVI __device__ __forceinline__

static constexpr int HIDDEN   = 2048;
static constexpr int NHEADS   = 16;
static constexpr int NKV      = 8;
static constexpr int HDIM     = 128;
static constexpr int QLEN     = 2048;
static constexpr int KVLEN    = 4096;
static constexpr int ENCLEN   = 512;
static constexpr int NREQ     = 8;
static constexpr float SCALING = 0.0625f;   // 256^-0.5
static constexpr float EPS     = 1e-6f;

DEVI unsigned short f2bf(float f) {
  unsigned int b = __float_as_uint(f);
  b += 0x7FFFu + ((b >> 16) & 1u);          // RNE
  return (unsigned short)(b >> 16);
}

DEVI void g2l16(const void* g, void* l) {
  __builtin_amdgcn_global_load_lds(
      (const __attribute__((address_space(1))) void*)g,
      (__attribute__((address_space(3))) void*)l, 16, 0, 0);
}

// ---------------- fused fp32 -> bf16 convert of all three inputs ----------------
__global__ __launch_bounds__(256) void cvt_all(const float* __restrict__ h,
                                               const float* __restrict__ e,
                                               const float* __restrict__ w,
                                               unsigned short* __restrict__ hb,
                                               unsigned short* __restrict__ eb,
                                               unsigned short* __restrict__ wb) {
  constexpr long S1 = (long)2048 * 2048, S2 = (long)4096 * 2048;
  long i = ((long)blockIdx.x * 256 + threadIdx.x) * 8;
  const float* src;
  unsigned short* dst;
  if (i < S1)           { src = h + i;            dst = hb + i; }
  else if (i < S1 + S2) { src = e + (i - S1);     dst = eb + (i - S1); }
  else                  { src = w + (i - S1 - S2); dst = wb + (i - S1 - S2); }
  float4 a = *(const float4*)src;
  float4 b = *(const float4*)(src + 4);
  short8 o;
  o[0] = (short)f2bf(a.x); o[1] = (short)f2bf(a.y);
  o[2] = (short)f2bf(a.z); o[3] = (short)f2bf(a.w);
  o[4] = (short)f2bf(b.x); o[5] = (short)f2bf(b.y);
  o[6] = (short)f2bf(b.z); o[7] = (short)f2bf(b.w);
  *(short8*)dst = o;
}

// ================= 128x128 GEMM: 768 blocks = exactly 3/CU =================
// 4 waves (2x2), wave tile 64x64, BK=32, ring-3 LDS (3 x 16KB = 48KB).
// XCD partition: each XCD owns a 16(bx) x 6(byy) RECTANGLE of tiles ->
// per-XCD L2 footprint 3MB A + 8MB B (R9's bx-major gave 24MB A -> 199MB
// FETCH, L3-feed-bound). Ring: stage t+2 into slot (t+2)%3; vmcnt(4) at top.
// N-span 128 = one head -> block-local RMS-norm / transpose epilogue.

#define SBAR  __builtin_amdgcn_s_barrier()

DEVI short8 rdfrag(const char* unit, int row, int lg) {
  int L = row >> 1;
  int g = ((row & 1) << 2) + lg;
  return *(const short8*)(unit + L * 128 + ((g ^ (L & 7)) << 4));
}

__global__ __launch_bounds__(256, 3) void gemm_qkv8(
    const unsigned short* __restrict__ Adec, const unsigned short* __restrict__ Aenc,
    const unsigned short* __restrict__ Bw,
    const float* __restrict__ q_nw, const float* __restrict__ k_nw,
    unsigned short* __restrict__ q_bf, unsigned short* __restrict__ k_bf,
    unsigned short* __restrict__ v_t) {
  extern __shared__ char lds[];
  const int K = 2048, NST = 64;   // 64 subtiles of K=32

  // rectangular XCD partition: xcd = flat&7 (dispatch round-robin);
  // each XCD gets bx 0..15 x byy xcd*6..xcd*6+5
  int flat = blockIdx.x;
  int xcd = flat & 7, i6 = flat >> 3;       // 96 blocks per XCD
  int bx = i6 & 15, byy = xcd * 6 + (i6 >> 4);

  const unsigned short* A;
  int bm0;
  if (byy < 16) { A = Adec; bm0 = byy * 128; }
  else          { A = Aenc; bm0 = (byy - 16) * 128; }
  const unsigned short* Bp = Bw + (byy < 16 ? 0 : (size_t)2048 * 2048);
  const int bn0 = bx * 128;

  const int tid = threadIdx.x, lane = tid & 63, wave = tid >> 6;
  const int lr = lane & 15, lg = lane >> 4;
  const int wr = wave >> 1, wc = wave & 1;   // 2M x 2N

  // stage source mapping for the 2 gload insts per unit (linear dest chunk ->
  // swizzled source row/col)
  int srow[2], scol[2];
#pragma unroll
  for (int i = 0; i < 2; ++i) {
    int sB = (i * 256 + tid) * 16;
    int sL = sB >> 7, sgp = (sB >> 4) & 7;
    int sg = sgp ^ (sL & 7);
    srow[i] = sL * 2 + (sg >> 2);
    scol[i] = (sg & 3) * 8;
  }
  const size_t aoff0 = (size_t)(bm0 + srow[0]) * K + scol[0];
  const size_t aoff1 = (size_t)(bm0 + srow[1]) * K + scol[1];
  const size_t boff0 = (size_t)(bn0 + srow[0]) * K + scol[0];
  const size_t boff1 = (size_t)(bn0 + srow[1]) * K + scol[1];
  const int dB = tid * 16;

#define STG4(t)                                                       \
  {                                                                   \
    const size_t kc = (size_t)(t) * 32;                               \
    char* base = lds + ((t) % 3) * 16384;                             \
    g2l16(A + aoff0 + kc,  base + dB);                                \
    g2l16(A + aoff1 + kc,  base + 4096 + dB);                         \
    g2l16(Bp + boff0 + kc, base + 8192 + dB);                         \
    g2l16(Bp + boff1 + kc, base + 12288 + dB);                        \
  }

  f32x4 acc[4][4] = {};

#define MM16(aS, bS)                                                  \
  {                                                                   \
    __builtin_amdgcn_s_setprio(1);                                    \
    _Pragma("unroll") for (int m = 0; m < 4; ++m)                     \
        _Pragma("unroll") for (int n = 0; n < 4; ++n)                 \
            acc[m][n] = __builtin_amdgcn_mfma_f32_16x16x32_bf16(      \
                aS[m], bS[n], acc[m][n], 0, 0, 0);                    \
    __builtin_amdgcn_s_setprio(0);                                    \
  }

  // ---- prologue: stage subtiles 0,1 ----
  STG4(0); STG4(1);

#pragma unroll 3
  for (int t = 0; t < NST - 1; ++t) {
    asm volatile("s_waitcnt vmcnt(4)" ::: "memory");
    SBAR;
    const char* ua = lds + (t % 3) * 16384;
    const char* ub = ua + 8192;
    short8 a[4], b[4];
#pragma unroll
    for (int m = 0; m < 4; ++m) a[m] = rdfrag(ua, wr * 64 + m * 16 + lr, lg);
#pragma unroll
    for (int n = 0; n < 4; ++n) b[n] = rdfrag(ub, wc * 64 + n * 16 + lr, lg);
    if (t < NST - 2) STG4(t + 2);
    MM16(a, b);
  }
  {  // t = 63: drain
    asm volatile("s_waitcnt vmcnt(0)" ::: "memory");
    SBAR;
    const char* ua = lds + ((NST - 1) % 3) * 16384;
    const char* ub = ua + 8192;
    short8 a[4], b[4];
#pragma unroll
    for (int m = 0; m < 4; ++m) a[m] = rdfrag(ua, wr * 64 + m * 16 + lr, lg);
#pragma unroll
    for (int n = 0; n < 4; ++n) b[n] = rdfrag(ub, wc * 64 + n * 16 + lr, lg);
    MM16(a, b);
  }

  // ================= fused epilogue: one head per block =================
  // tile row = wr*64 + m*16 + lg*4 + r (token), col = wc*64 + n*16 + lr (dim)
  const int btype = (byy < 16) ? 0 : (bx < 8 ? 1 : 2);  // 0=Q,1=K,2=V

  if (btype < 2) {
    float* Lf = (float*)lds;                 // [64][132] f32 = 33.8KB
    const float* wnorm = (btype == 0) ? q_nw : k_nw;
    const float fscale = (btype == 0) ? SCALING : 1.0f;
    unsigned short* dst = (btype == 0) ? q_bf : k_bf;
    const size_t LEN = (btype == 0) ? (size_t)QLEN : (size_t)KVLEN;
    const int g16 = tid >> 4, l16 = tid & 15;
    const int dloc = l16 * 8;
    float wv[8];
#pragma unroll
    for (int j = 0; j < 8; ++j) wv[j] = 1.0f + wnorm[dloc + j];

#pragma unroll
    for (int hh = 0; hh < 2; ++hh) {
      SBAR;
      if (wr == hh) {
#pragma unroll
        for (int m = 0; m < 4; ++m)
#pragma unroll
          for (int n = 0; n < 4; ++n)
#pragma unroll
            for (int r = 0; r < 4; ++r)
              Lf[(m * 16 + lg * 4 + r) * 132 + wc * 64 + n * 16 + lr] =
                  acc[m][n][r];
      }
      SBAR;
#pragma unroll
      for (int it = 0; it < 4; ++it) {
        int row = it * 16 + g16;
        const float* src = &Lf[row * 132 + dloc];
        f32x4 x0 = *(const f32x4*)src;
        f32x4 x1 = *(const f32x4*)(src + 4);
        float ssq = x0[0]*x0[0] + x0[1]*x0[1] + x0[2]*x0[2] + x0[3]*x0[3] +
                    x1[0]*x1[0] + x1[1]*x1[1] + x1[2]*x1[2] + x1[3]*x1[3];
#pragma unroll
        for (int msk = 8; msk >= 1; msk >>= 1) ssq += __shfl_xor(ssq, msk);
        float sc = rsqrtf(ssq * (1.0f / 128.0f) + EPS) * fscale;
        short8 o;
        o[0] = (short)f2bf(x0[0] * sc * wv[0]); o[1] = (short)f2bf(x0[1] * sc * wv[1]);
        o[2] = (short)f2bf(x0[2] * sc * wv[2]); o[3] = (short)f2bf(x0[3] * sc * wv[3]);
        o[4] = (short)f2bf(x1[0] * sc * wv[4]); o[5] = (short)f2bf(x1[1] * sc * wv[5]);
        o[6] = (short)f2bf(x1[2] * sc * wv[6]); o[7] = (short)f2bf(x1[3] * sc * wv[7]);
        int tok = bm0 + hh * 64 + row;
        *(short8*)&dst[((size_t)bx * LEN + tok) * 128 + dloc] = o;
      }
    }
  } else {
    float* Lv = (float*)lds;                 // [128 d][66] f32 = 33.8KB
    const int kh = bx - 8;
#pragma unroll
    for (int hh = 0; hh < 2; ++hh) {
      SBAR;
      if (wr == hh) {
#pragma unroll
        for (int m = 0; m < 4; ++m)
#pragma unroll
          for (int n = 0; n < 4; ++n)
            *(f32x4*)&Lv[(wc * 64 + n * 16 + lr) * 66 + m * 16 + lg * 4] =
                acc[m][n];
      }
      SBAR;
      int d = tid >> 1, th = tid & 1;        // d 0..127, token half of 32
      const float* src = &Lv[d * 66 + th * 32];
      int tok0 = bm0 + hh * 64 + th * 32;
      unsigned short* vp = &v_t[((size_t)kh * 128 + d) * KVLEN + tok0];
#pragma unroll
      for (int j = 0; j < 4; ++j) {
        f32x4 v0 = *(const f32x4*)(src + j * 8);
        f32x4 v1 = *(const f32x4*)(src + j * 8 + 4);
        short8 o;
        o[0] = (short)f2bf(v0[0]); o[1] = (short)f2bf(v0[1]);
        o[2] = (short)f2bf(v0[2]); o[3] = (short)f2bf(v0[3]);
        o[4] = (short)f2bf(v1[0]); o[5] = (short)f2bf(v1[1]);
        o[6] = (short)f2bf(v1[2]); o[7] = (short)f2bf(v1[3]);
        *(short8*)(vp + j * 8) = o;
      }
    }
  }
#undef STG4
#undef MM16
}

// ---------------- attention: K/V chunk double-buffer, 1 barrier/chunk ----------------
// grid (32 qtiles, 16 heads); block 256 = 4 waves x 16 q-rows; 8 KV chunks of 64.
// smem: Ks[2] @0 (2x16KB), Vs[2] @32768 (2x16KB), Ps @65536 (8KB) = 72KB.
__global__ __launch_bounds__(256, 4) void attn_kernel(
    const unsigned short* __restrict__ qb,   // [16][2048][128]
    const unsigned short* __restrict__ kb,   // [8][4096][128]
    const unsigned short* __restrict__ vt,   // [8][128][4096]
    const int* __restrict__ seq_lens,
    float* __restrict__ out) {               // [2048][2048]
  __shared__ __align__(16) char smem[73728];

  const int h = blockIdx.y;
  const int t0 = blockIdx.x * 64;
  int req = 0, qs = 0;
#pragma unroll 1
  while (req < NREQ - 1 && qs + seq_lens[req] <= t0) { qs += seq_lens[req]; ++req; }
  const int slen = seq_lens[req];
  const int rows = min(64, qs + slen - t0);
  if (rows <= 0) return;
  const int qbase = t0;

  const int tid = threadIdx.x, lane = tid & 63, wave = tid >> 6;
  const int lr = lane & 15, lg = lane >> 4;
  const int m0w = wave * 16;
  const int kh = h >> 1;
  const int kv0 = req * ENCLEN;

#define STAGE_K(c, db)                                                        \
  _Pragma("unroll") for (int i = 0; i < 4; ++i) {                             \
    int idx = i * 256 + tid;                                                  \
    int row = idx >> 4, slot = idx & 15;                                      \
    g2l16(kb + ((size_t)kh * KVLEN + kv0 + (c) * 64 + row) * 128 +            \
              ((slot ^ (row & 15)) << 3),                                     \
          smem + (db) * 16384 + idx * 16);                                    \
  }
#define STAGE_V(c, db)                                                        \
  _Pragma("unroll") for (int i = 0; i < 4; ++i) {                             \
    int idx = i * 256 + tid;                                                  \
    int row = idx >> 3, slot = idx & 7;                                       \
    g2l16(vt + ((size_t)kh * 128 + row) * KVLEN + kv0 + (c) * 64 +            \
              ((slot ^ (row & 7)) << 3),                                      \
          smem + 32768 + (db) * 16384 + idx * 16);                            \
  }

  unsigned short* Ps = (unsigned short*)(smem + 65536);

  short8 a_q[4];
  {
    int qr = qbase + min(m0w + lr, rows - 1);
    const unsigned short* qp = qb + ((size_t)h * QLEN + qr) * 128 + lg * 8;
#pragma unroll
    for (int ks = 0; ks < 4; ++ks) a_q[ks] = *(const short8*)(qp + ks * 32);
  }

  f32x4 acc[8] = {};
  float mrow[4], lsum[4];
#pragma unroll
  for (int r = 0; r < 4; ++r) { mrow[r] = -1e30f; lsum[r] = 0.f; }

  // prologue: stage chunk 0 into buffer 0
  STAGE_K(0, 0); STAGE_V(0, 0);

  int cb = 0;
#pragma unroll 1
  for (int c = 0; c < 8; ++c) {
    asm volatile("s_waitcnt vmcnt(0)" ::: "memory");
    __syncthreads();
    if (c < 7) { STAGE_K(c + 1, cb ^ 1); STAGE_V(c + 1, cb ^ 1); }
    const unsigned short* Kb = (const unsigned short*)(smem + cb * 16384);
    const unsigned short* Vb = (const unsigned short*)(smem + 32768 + cb * 16384);

    f32x4 s[4] = {};
#pragma unroll
    for (int ks = 0; ks < 4; ++ks) {
      short8 bk[4];
#pragma unroll
      for (int n = 0; n < 4; ++n) {
        int row = n * 16 + lr;
        bk[n] = *(const short8*)&Kb[row * 128 + (((ks * 4 + lg) ^ (row & 15)) << 3)];
      }
#pragma unroll
      for (int n = 0; n < 4; ++n)
        s[n] = __builtin_amdgcn_mfma_f32_16x16x32_bf16(a_q[ks], bk[n], s[n], 0, 0, 0);
    }

#pragma unroll
    for (int r = 0; r < 4; ++r) {
      float mx = fmaxf(fmaxf(s[0][r], s[1][r]), fmaxf(s[2][r], s[3][r]));
#pragma unroll
      for (int msk = 8; msk >= 1; msk >>= 1) mx = fmaxf(mx, __shfl_xor(mx, msk));
      float mnew = fmaxf(mrow[r], mx);
      float al = __expf(mrow[r] - mnew);
      mrow[r] = mnew;
      float rs = 0.f;
#pragma unroll
      for (int n = 0; n < 4; ++n) {
        float p = __expf(s[n][r] - mnew);
        s[n][r] = p;
        rs += p;
      }
#pragma unroll
      for (int msk = 8; msk >= 1; msk >>= 1) rs += __shfl_xor(rs, msk);
      lsum[r] = lsum[r] * al + rs;
#pragma unroll
      for (int n2 = 0; n2 < 8; ++n2) acc[n2][r] *= al;
    }

#pragma unroll
    for (int n = 0; n < 4; ++n)
#pragma unroll
      for (int r = 0; r < 4; ++r) {
        int row = m0w + lg * 4 + r;
        int col = n * 16 + lr;
        Ps[row * 64 + (col ^ ((row & 7) << 3))] = f2bf(s[n][r]);
      }
    asm volatile("s_waitcnt lgkmcnt(0)" ::: "memory");
    __builtin_amdgcn_sched_barrier(0);

#pragma unroll
    for (int ks = 0; ks < 2; ++ks) {
      int prow = m0w + lr;
      short8 pa = *(const short8*)&Ps[prow * 64 + (((ks * 4 + lg) ^ (prow & 7)) << 3)];
#pragma unroll
      for (int n2 = 0; n2 < 8; ++n2) {
        int row = n2 * 16 + lr;
        short8 bv = *(const short8*)&Vb[row * 64 + (((ks * 4 + lg) ^ (row & 7)) << 3)];
        acc[n2] = __builtin_amdgcn_mfma_f32_16x16x32_bf16(pa, bv, acc[n2], 0, 0, 0);
      }
    }
    cb ^= 1;
  }
  __syncthreads();

  // normalize in-register, restage via LDS, store fp32 out directly
  float inv[4];
#pragma unroll
  for (int r = 0; r < 4; ++r) inv[r] = 1.0f / lsum[r];
#pragma unroll
  for (int n2 = 0; n2 < 8; ++n2)
#pragma unroll
    for (int r = 0; r < 4; ++r) acc[n2][r] *= inv[r];

  constexpr int OFS = 132;
  float* Of = (float*)smem;                  // 64*132*4 = 33.8KB
#pragma unroll
  for (int n2 = 0; n2 < 8; ++n2)
#pragma unroll
    for (int r = 0; r < 4; ++r)
      Of[(m0w + lg * 4 + r) * OFS + n2 * 16 + lr] = acc[n2][r];
  __syncthreads();
#pragma unroll
  for (int p = 0; p < 8; ++p) {
    int idx = p * 256 + tid;
    int row = idx >> 5, c4 = (idx & 31) * 4;
    if (row < rows) {
      f32x4 v = *(const f32x4*)&Of[row * OFS + c4];
      *(f32x4*)&out[(size_t)(qbase + row) * 2048 + h * 128 + c4] = v;
    }
  }
#undef STAGE_K
#undef STAGE_V
}

// ---------------- launch ----------------
extern "C" void kernel_launch(void* const* d_in, const int* in_sizes, int n_in,
                              void* d_out, int out_size, void* d_ws, size_t ws_size,
                              hipStream_t stream) {
  const float* hidden = (const float*)d_in[0];
  const float* enc    = (const float*)d_in[1];
  const float* w_qkv  = (const float*)d_in[2];
  const float* q_nw   = (const float*)d_in[3];
  const float* k_nw   = (const float*)d_in[4];
  const int*   slens  = (const int*)d_in[5];
  float* out = (float*)d_out;

  char* ws = (char*)d_ws;
  unsigned short* h_bf = (unsigned short*)(ws + 0);           //  8.39 MB
  unsigned short* e_bf = (unsigned short*)(ws + 8388608);     // 16.78 MB
  unsigned short* w_bf = (unsigned short*)(ws + 25165824);    // 16.78 MB
  unsigned short* q_bf = (unsigned short*)(ws + 41943040);    //  8.39 MB
  unsigned short* k_bf = (unsigned short*)(ws + 50331648);    //  8.39 MB
  unsigned short* v_t  = (unsigned short*)(ws + 58720256);    //  8.39 MB (ends 67.1MB)

  static bool attr_set = false;
  if (!attr_set) {
    hipFuncSetAttribute((const void*)gemm_qkv8,
                        hipFuncAttributeMaxDynamicSharedMemorySize, 49152);
    attr_set = true;
  }

  cvt_all<<<10240, 256, 0, stream>>>(hidden, enc, w_qkv, h_bf, e_bf, w_bf);

  gemm_qkv8<<<768, 256, 49152, stream>>>(h_bf, e_bf, w_bf, q_nw, k_nw,
                                         q_bf, k_bf, v_t);

  attn_kernel<<<dim3(32, 16), 256, 0, stream>>>(q_bf, k_bf, v_t, slens, out);
}

// Round 11
// 104.980 us; speedup vs baseline: 1.1242x; 1.0884x over previous
//
#include <hip/hip_runtime.h>

typedef __attribute__((ext_vector_type(8))) short short8;
typedef __attribute__((ext_vector_type(4))) float f32x4;

#define DEVI __device__ __forceinline__

static constexpr int HIDDEN   = 2048;
static constexpr int NHEADS   = 16;
static constexpr int NKV      = 8;
static constexpr int HDIM     = 128;
static constexpr int QLEN     = 2048;
static constexpr int KVLEN    = 4096;
static constexpr int ENCLEN   = 512;
static constexpr int NREQ     = 8;
static constexpr float SCALING = 0.0625f;   // 256^-0.5
static constexpr float EPS     = 1e-6f;

DEVI unsigned short f2bf(float f) {
  unsigned int b = __float_as_uint(f);
  b += 0x7FFFu + ((b >> 16) & 1u);          // RNE
  return (unsigned short)(b >> 16);
}

DEVI unsigned cvtpk(float lo, float hi) {   // packed f32x2 -> bf16x2 (RNE)
  unsigned r;
  asm("v_cvt_pk_bf16_f32 %0, %1, %2" : "=v"(r) : "v"(lo), "v"(hi));
  return r;
}

DEVI void g2l16(const void* g, void* l) {
  __builtin_amdgcn_global_load_lds(
      (const __attribute__((address_space(1))) void*)g,
      (__attribute__((address_space(3))) void*)l, 16, 0, 0);
}

// ================= 256x256 GEMM (R8 structure) + fused fp32->bf16 staging ======
// BK=32 subtiles, ring-3 LDS (3 x 32KB), 512 thr = 8 waves (2M x 4N), 1 barrier
// per subtile. Staging is now REG-STAGED from the ORIGINAL fp32 inputs:
//   top of iter t:    issue 8 float4 loads (fp32, swizzled-source coords) for t+2
//   bottom of iter t: v_cvt_pk_bf16_f32 -> 4x ds_write_b128 (linear dest)
//   lgkmcnt(0) before the barrier publishes the writes to all waves.
// This deletes the standalone cvt_all kernel (19us) at the cost of fp32 fetch.
// Ring/WAR proof unchanged from R8: write slot (t+2)%3 == slot read at t-1,
// whose reads completed before this iteration's start barrier.

#define SBAR  __builtin_amdgcn_s_barrier()
#define LGKMB { asm volatile("s_waitcnt lgkmcnt(0)" ::: "memory"); }

DEVI short8 rdfrag(const char* unit, int row, int lg) {
  int L = row >> 1;
  int g = ((row & 1) << 2) + lg;
  return *(const short8*)(unit + L * 128 + ((g ^ (L & 7)) << 4));
}

__global__ __launch_bounds__(512, 2) void gemm_qkv8(
    const float* __restrict__ Adec, const float* __restrict__ Aenc,
    const float* __restrict__ Ww,
    const float* __restrict__ q_nw, const float* __restrict__ k_nw,
    unsigned short* __restrict__ q_bf, unsigned short* __restrict__ k_bf,
    unsigned short* __restrict__ v_t) {
  extern __shared__ char lds[];
  const int K = 2048, NST = 64;   // 64 subtiles of K=32

  // XCD swizzle over 192 = 8*24 (R8's, measured 49MB bf16 FETCH)
  int flat = blockIdx.y * 8 + blockIdx.x;
  int swz = (flat & 7) * 24 + (flat >> 3);
  int bx = swz & 7, by = swz >> 3;

  const float* A;
  int bm0;
  if (by < 8) { A = Adec; bm0 = by * 256; }
  else        { A = Aenc; bm0 = (by - 8) * 256; }
  const float* Bp = Ww + (by < 8 ? 0 : (size_t)2048 * 2048);
  const int bn0 = bx * 256;

  const int tid = threadIdx.x, lane = tid & 63, wave = tid >> 6;
  const int lr = lane & 15, lg = lane >> 4;
  const int wr = wave >> 2, wc = wave & 3;   // 2M x 4N
  const int bq = (wc & 1) * 64;

  // staging source mapping: linear dest chunk tid*16 -> swizzled source row/col
  const int sB = tid * 16;
  const int sL = sB >> 7, sgp = (sB >> 4) & 7;
  const int sg = sgp ^ (sL & 7);
  const int st_row = sL * 2 + (sg >> 2);
  const int st_col = (sg & 3) * 8;
  const size_t a0off = (size_t)(bm0 + st_row) * K + st_col;       // fp32 elems
  const size_t a1off = a0off + (size_t)128 * K;
  const size_t b0off = (size_t)(bn0 + st_row) * K + st_col;
  const size_t b1off = b0off + (size_t)128 * K;

  f32x4 acc[8][4] = {};

#define MM(mq, aS, bS)                                                \
  {                                                                   \
    __builtin_amdgcn_s_setprio(1);                                    \
    _Pragma("unroll") for (int m = 0; m < 4; ++m)                     \
        _Pragma("unroll") for (int n = 0; n < 4; ++n)                 \
            acc[(mq)*4 + m][n] = __builtin_amdgcn_mfma_f32_16x16x32_bf16( \
                aS[m], bS[n], acc[(mq)*4 + m][n], 0, 0, 0);           \
    __builtin_amdgcn_s_setprio(0);                                    \
  }

  // load 8 float4 (fp32 source for one subtile's 4 units), cvt, write 4x b128
#define STAGE_LOAD(t, R)                                              \
  {                                                                   \
    const size_t kc = (size_t)(t) * 32;                               \
    R[0] = *(const f32x4*)(A + a0off + kc);                           \
    R[1] = *(const f32x4*)(A + a0off + kc + 4);                       \
    R[2] = *(const f32x4*)(A + a1off + kc);                           \
    R[3] = *(const f32x4*)(A + a1off + kc + 4);                       \
    R[4] = *(const f32x4*)(Bp + b0off + kc);                          \
    R[5] = *(const f32x4*)(Bp + b0off + kc + 4);                      \
    R[6] = *(const f32x4*)(Bp + b1off + kc);                          \
    R[7] = *(const f32x4*)(Bp + b1off + kc + 4);                      \
  }
#define STAGE_WRITE(t, R)                                             \
  {                                                                   \
    char* base = lds + ((t) % 3) * 32768;                             \
    _Pragma("unroll") for (int u = 0; u < 4; ++u) {                   \
      unsigned w0 = cvtpk(R[u * 2][0], R[u * 2][1]);                  \
      unsigned w1 = cvtpk(R[u * 2][2], R[u * 2][3]);                  \
      unsigned w2 = cvtpk(R[u * 2 + 1][0], R[u * 2 + 1][1]);          \
      unsigned w3 = cvtpk(R[u * 2 + 1][2], R[u * 2 + 1][3]);          \
      uint4 pk = make_uint4(w0, w1, w2, w3);                          \
      *(uint4*)(base + u * 8192 + sB) = pk;                           \
    }                                                                 \
  }

  // ---- prologue: fill slots 0,1 ----
  {
    f32x4 R[8];
    STAGE_LOAD(0, R); STAGE_WRITE(0, R);
    STAGE_LOAD(1, R); STAGE_WRITE(1, R);
  }
  LGKMB; SBAR;

#pragma unroll 3
  for (int t = 0; t < NST - 1; ++t) {
    f32x4 R[8];
    if (t < NST - 2) STAGE_LOAD(t + 2, R);
    const char* ua = lds + (t % 3) * 32768 + wr * 8192;
    const char* ub = lds + (t % 3) * 32768 + 16384 + ((wc >> 1) << 13);
    short8 a0[4], b0[4], a1[4];
#pragma unroll
    for (int m = 0; m < 4; ++m) a0[m] = rdfrag(ua, m * 16 + lr, lg);
#pragma unroll
    for (int n = 0; n < 4; ++n) b0[n] = rdfrag(ub, bq + n * 16 + lr, lg);
    MM(0, a0, b0);
#pragma unroll
    for (int m = 0; m < 4; ++m) a1[m] = rdfrag(ua, 64 + m * 16 + lr, lg);
    MM(1, a1, b0);
    if (t < NST - 2) STAGE_WRITE(t + 2, R);
    LGKMB; SBAR;
  }
  {  // t = 63
    const char* ua = lds + ((NST - 1) % 3) * 32768 + wr * 8192;
    const char* ub = lds + ((NST - 1) % 3) * 32768 + 16384 + ((wc >> 1) << 13);
    short8 a0[4], b0[4], a1[4];
#pragma unroll
    for (int m = 0; m < 4; ++m) a0[m] = rdfrag(ua, m * 16 + lr, lg);
#pragma unroll
    for (int n = 0; n < 4; ++n) b0[n] = rdfrag(ub, bq + n * 16 + lr, lg);
    MM(0, a0, b0);
#pragma unroll
    for (int m = 0; m < 4; ++m) a1[m] = rdfrag(ua, 64 + m * 16 + lr, lg);
    MM(1, a1, b0);
  }

  // ================= fused epilogue (R8's, unchanged) =================
  const int btype = (by < 8) ? 0 : (bx < 4 ? 1 : 2);  // 0=Q,1=K,2=V
  const int tokbase0 = (by < 8 ? by : by - 8) * 256;

  if (btype < 2) {
    float* Lf = (float*)lds;                 // [64][260] f32
    const float* wnorm = (btype == 0) ? q_nw : k_nw;
    const float fscale = (btype == 0) ? SCALING : 1.0f;
    unsigned short* dst = (btype == 0) ? q_bf : k_bf;
    const size_t LEN = (btype == 0) ? (size_t)QLEN : (size_t)KVLEN;
    const int dloc = lr * 8;
    float wv[8];
#pragma unroll
    for (int j = 0; j < 8; ++j) wv[j] = 1.0f + wnorm[dloc + j];

#pragma unroll
    for (int q = 0; q < 4; ++q) {
      SBAR;
      if (wr == (q >> 1)) {
        const int amb = (q & 1) * 4;
#pragma unroll
        for (int am2 = 0; am2 < 4; ++am2)
#pragma unroll
          for (int n = 0; n < 4; ++n)
#pragma unroll
            for (int r = 0; r < 4; ++r)
              Lf[(am2 * 16 + lg * 4 + r) * 260 + wc * 64 + n * 16 + lr] =
                  acc[amb + am2][n][r];
      }
      SBAR;
#pragma unroll
      for (int it = 0; it < 4; ++it) {
        int pair = it * 32 + wave * 4 + (lane >> 4);   // 0..127
        int row = pair >> 1, hh = pair & 1;
        const float* src = &Lf[row * 260 + hh * 128 + dloc];
        f32x4 x0 = *(const f32x4*)src;
        f32x4 x1 = *(const f32x4*)(src + 4);
        float ssq = x0[0]*x0[0] + x0[1]*x0[1] + x0[2]*x0[2] + x0[3]*x0[3] +
                    x1[0]*x1[0] + x1[1]*x1[1] + x1[2]*x1[2] + x1[3]*x1[3];
#pragma unroll
        for (int m = 8; m >= 1; m >>= 1) ssq += __shfl_xor(ssq, m);
        float sc = rsqrtf(ssq * (1.0f / 128.0f) + EPS) * fscale;
        short8 o;
        o[0] = (short)f2bf(x0[0] * sc * wv[0]); o[1] = (short)f2bf(x0[1] * sc * wv[1]);
        o[2] = (short)f2bf(x0[2] * sc * wv[2]); o[3] = (short)f2bf(x0[3] * sc * wv[3]);
        o[4] = (short)f2bf(x1[0] * sc * wv[4]); o[5] = (short)f2bf(x1[1] * sc * wv[5]);
        o[6] = (short)f2bf(x1[2] * sc * wv[6]); o[7] = (short)f2bf(x1[3] * sc * wv[7]);
        int tok = tokbase0 + q * 64 + row;
        int hd = 2 * bx + hh;
        *(short8*)&dst[((size_t)hd * LEN + tok) * 128 + dloc] = o;
      }
    }
  } else {
    float* Lv = (float*)lds;                 // [256 d][68] f32 (col-major quarter)
#pragma unroll
    for (int q = 0; q < 4; ++q) {
      SBAR;
      if (wr == (q >> 1)) {
        const int amb = (q & 1) * 4;
#pragma unroll
        for (int am2 = 0; am2 < 4; ++am2)
#pragma unroll
          for (int n = 0; n < 4; ++n)
            *(f32x4*)&Lv[(wc * 64 + n * 16 + lr) * 68 + am2 * 16 + lg * 4] =
                acc[amb + am2][n];
      }
      SBAR;
      int d = tid >> 1, th = tid & 1;        // d 0..255, token half
      const float* src = &Lv[d * 68 + th * 32];
      int kh = (bx - 4) * 2 + (d >> 7);
      int tok = tokbase0 + q * 64 + th * 32;
      unsigned short* vp = &v_t[((size_t)kh * 128 + (d & 127)) * KVLEN + tok];
#pragma unroll
      for (int j = 0; j < 4; ++j) {
        f32x4 v0 = *(const f32x4*)(src + j * 8);
        f32x4 v1 = *(const f32x4*)(src + j * 8 + 4);
        short8 o;
        o[0] = (short)f2bf(v0[0]); o[1] = (short)f2bf(v0[1]);
        o[2] = (short)f2bf(v0[2]); o[3] = (short)f2bf(v0[3]);
        o[4] = (short)f2bf(v1[0]); o[5] = (short)f2bf(v1[1]);
        o[6] = (short)f2bf(v1[2]); o[7] = (short)f2bf(v1[3]);
        *(short8*)(vp + j * 8) = o;
      }
    }
  }
#undef MM
#undef STAGE_LOAD
#undef STAGE_WRITE
}

// ---------------- attention: K/V chunk double-buffer, 1 barrier/chunk ----------------
// grid (32 qtiles, 16 heads); block 256 = 4 waves x 16 q-rows; 8 KV chunks of 64.
// smem: Ks[2] @0 (2x16KB), Vs[2] @32768 (2x16KB), Ps @65536 (8KB) = 72KB.
__global__ __launch_bounds__(256, 4) void attn_kernel(
    const unsigned short* __restrict__ qb,   // [16][2048][128]
    const unsigned short* __restrict__ kb,   // [8][4096][128]
    const unsigned short* __restrict__ vt,   // [8][128][4096]
    const int* __restrict__ seq_lens,
    float* __restrict__ out) {               // [2048][2048]
  __shared__ __align__(16) char smem[73728];

  const int h = blockIdx.y;
  const int t0 = blockIdx.x * 64;
  int req = 0, qs = 0;
#pragma unroll 1
  while (req < NREQ - 1 && qs + seq_lens[req] <= t0) { qs += seq_lens[req]; ++req; }
  const int slen = seq_lens[req];
  const int rows = min(64, qs + slen - t0);
  if (rows <= 0) return;
  const int qbase = t0;

  const int tid = threadIdx.x, lane = tid & 63, wave = tid >> 6;
  const int lr = lane & 15, lg = lane >> 4;
  const int m0w = wave * 16;
  const int kh = h >> 1;
  const int kv0 = req * ENCLEN;

#define STAGE_K(c, db)                                                        \
  _Pragma("unroll") for (int i = 0; i < 4; ++i) {                             \
    int idx = i * 256 + tid;                                                  \
    int row = idx >> 4, slot = idx & 15;                                      \
    g2l16(kb + ((size_t)kh * KVLEN + kv0 + (c) * 64 + row) * 128 +            \
              ((slot ^ (row & 15)) << 3),                                     \
          smem + (db) * 16384 + idx * 16);                                    \
  }
#define STAGE_V(c, db)                                                        \
  _Pragma("unroll") for (int i = 0; i < 4; ++i) {                             \
    int idx = i * 256 + tid;                                                  \
    int row = idx >> 3, slot = idx & 7;                                       \
    g2l16(vt + ((size_t)kh * 128 + row) * KVLEN + kv0 + (c) * 64 +            \
              ((slot ^ (row & 7)) << 3),                                      \
          smem + 32768 + (db) * 16384 + idx * 16);                            \
  }

  unsigned short* Ps = (unsigned short*)(smem + 65536);

  short8 a_q[4];
  {
    int qr = qbase + min(m0w + lr, rows - 1);
    const unsigned short* qp = qb + ((size_t)h * QLEN + qr) * 128 + lg * 8;
#pragma unroll
    for (int ks = 0; ks < 4; ++ks) a_q[ks] = *(const short8*)(qp + ks * 32);
  }

  f32x4 acc[8] = {};
  float mrow[4], lsum[4];
#pragma unroll
  for (int r = 0; r < 4; ++r) { mrow[r] = -1e30f; lsum[r] = 0.f; }

  // prologue: stage chunk 0 into buffer 0
  STAGE_K(0, 0); STAGE_V(0, 0);

  int cb = 0;
#pragma unroll 1
  for (int c = 0; c < 8; ++c) {
    asm volatile("s_waitcnt vmcnt(0)" ::: "memory");
    __syncthreads();
    if (c < 7) { STAGE_K(c + 1, cb ^ 1); STAGE_V(c + 1, cb ^ 1); }
    const unsigned short* Kb = (const unsigned short*)(smem + cb * 16384);
    const unsigned short* Vb = (const unsigned short*)(smem + 32768 + cb * 16384);

    f32x4 s[4] = {};
#pragma unroll
    for (int ks = 0; ks < 4; ++ks) {
      short8 bk[4];
#pragma unroll
      for (int n = 0; n < 4; ++n) {
        int row = n * 16 + lr;
        bk[n] = *(const short8*)&Kb[row * 128 + (((ks * 4 + lg) ^ (row & 15)) << 3)];
      }
#pragma unroll
      for (int n = 0; n < 4; ++n)
        s[n] = __builtin_amdgcn_mfma_f32_16x16x32_bf16(a_q[ks], bk[n], s[n], 0, 0, 0);
    }

#pragma unroll
    for (int r = 0; r < 4; ++r) {
      float mx = fmaxf(fmaxf(s[0][r], s[1][r]), fmaxf(s[2][r], s[3][r]));
#pragma unroll
      for (int msk = 8; msk >= 1; msk >>= 1) mx = fmaxf(mx, __shfl_xor(mx, msk));
      float mnew = fmaxf(mrow[r], mx);
      float al = __expf(mrow[r] - mnew);
      mrow[r] = mnew;
      float rs = 0.f;
#pragma unroll
      for (int n = 0; n < 4; ++n) {
        float p = __expf(s[n][r] - mnew);
        s[n][r] = p;
        rs += p;
      }
#pragma unroll
      for (int msk = 8; msk >= 1; msk >>= 1) rs += __shfl_xor(rs, msk);
      lsum[r] = lsum[r] * al + rs;
#pragma unroll
      for (int n2 = 0; n2 < 8; ++n2) acc[n2][r] *= al;
    }

#pragma unroll
    for (int n = 0; n < 4; ++n)
#pragma unroll
      for (int r = 0; r < 4; ++r) {
        int row = m0w + lg * 4 + r;
        int col = n * 16 + lr;
        Ps[row * 64 + (col ^ ((row & 7) << 3))] = f2bf(s[n][r]);
      }
    asm volatile("s_waitcnt lgkmcnt(0)" ::: "memory");
    __builtin_amdgcn_sched_barrier(0);

#pragma unroll
    for (int ks = 0; ks < 2; ++ks) {
      int prow = m0w + lr;
      short8 pa = *(const short8*)&Ps[prow * 64 + (((ks * 4 + lg) ^ (prow & 7)) << 3)];
#pragma unroll
      for (int n2 = 0; n2 < 8; ++n2) {
        int row = n2 * 16 + lr;
        short8 bv = *(const short8*)&Vb[row * 64 + (((ks * 4 + lg) ^ (row & 7)) << 3)];
        acc[n2] = __builtin_amdgcn_mfma_f32_16x16x32_bf16(pa, bv, acc[n2], 0, 0, 0);
      }
    }
    cb ^= 1;
  }
  __syncthreads();

  // normalize in-register, restage via LDS, store fp32 out directly
  float inv[4];
#pragma unroll
  for (int r = 0; r < 4; ++r) inv[r] = 1.0f / lsum[r];
#pragma unroll
  for (int n2 = 0; n2 < 8; ++n2)
#pragma unroll
    for (int r = 0; r < 4; ++r) acc[n2][r] *= inv[r];

  constexpr int OFS = 132;
  float* Of = (float*)smem;                  // 64*132*4 = 33.8KB
#pragma unroll
  for (int n2 = 0; n2 < 8; ++n2)
#pragma unroll
    for (int r = 0; r < 4; ++r)
      Of[(m0w + lg * 4 + r) * OFS + n2 * 16 + lr] = acc[n2][r];
  __syncthreads();
#pragma unroll
  for (int p = 0; p < 8; ++p) {
    int idx = p * 256 + tid;
    int row = idx >> 5, c4 = (idx & 31) * 4;
    if (row < rows) {
      f32x4 v = *(const f32x4*)&Of[row * OFS + c4];
      *(f32x4*)&out[(size_t)(qbase + row) * 2048 + h * 128 + c4] = v;
    }
  }
#undef STAGE_K
#undef STAGE_V
}

// ---------------- launch ----------------
extern "C" void kernel_launch(void* const* d_in, const int* in_sizes, int n_in,
                              void* d_out, int out_size, void* d_ws, size_t ws_size,
                              hipStream_t stream) {
  const float* hidden = (const float*)d_in[0];
  const float* enc    = (const float*)d_in[1];
  const float* w_qkv  = (const float*)d_in[2];
  const float* q_nw   = (const float*)d_in[3];
  const float* k_nw   = (const float*)d_in[4];
  const int*   slens  = (const int*)d_in[5];
  float* out = (float*)d_out;

  char* ws = (char*)d_ws;
  unsigned short* q_bf = (unsigned short*)(ws + 0);           //  8.39 MB
  unsigned short* k_bf = (unsigned short*)(ws + 8388608);     //  8.39 MB
  unsigned short* v_t  = (unsigned short*)(ws + 16777216);    //  8.39 MB (ends 25.2MB)

  static bool attr_set = false;
  if (!attr_set) {
    hipFuncSetAttribute((const void*)gemm_qkv8,
                        hipFuncAttributeMaxDynamicSharedMemorySize, 131072);
    attr_set = true;
  }

  gemm_qkv8<<<dim3(8, 24), 512, 131072, stream>>>(hidden, enc, w_qkv, q_nw, k_nw,
                                                  q_bf, k_bf, v_t);

  attn_kernel<<<dim3(32, 16), 256, 0, stream>>>(q_bf, k_bf, v_t, slens, out);
}

// Round 12
// 104.097 us; speedup vs baseline: 1.1338x; 1.0085x over previous
//
#include <hip/hip_runtime.h>

typedef __attribute__((ext_vector_type(8))) short short8;
typedef __attribute__((ext_vector_type(4))) float f32x4;

#define DEVI __device__ __forceinline__

static constexpr int HIDDEN   = 2048;
static constexpr int NHEADS   = 16;
static constexpr int NKV      = 8;
static constexpr int HDIM     = 128;
static constexpr int QLEN     = 2048;
static constexpr int KVLEN    = 4096;
static constexpr int ENCLEN   = 512;
static constexpr int NREQ     = 8;
static constexpr float SCALING = 0.0625f;   // 256^-0.5
static constexpr float EPS     = 1e-6f;

DEVI unsigned short f2bf(float f) {
  unsigned int b = __float_as_uint(f);
  b += 0x7FFFu + ((b >> 16) & 1u);          // RNE
  return (unsigned short)(b >> 16);
}

DEVI unsigned cvtpk(float lo, float hi) {   // packed f32x2 -> bf16x2 (RNE)
  unsigned r;
  asm("v_cvt_pk_bf16_f32 %0, %1, %2" : "=v"(r) : "v"(lo), "v"(hi));
  return r;
}

DEVI void g2l16(const void* g, void* l) {
  __builtin_amdgcn_global_load_lds(
      (const __attribute__((address_space(1))) void*)g,
      (__attribute__((address_space(3))) void*)l, 16, 0, 0);
}

// ================= 256x256 GEMM + fused fp32->bf16 staging (carried T14) =======
// BK=32 subtiles, ring-3 LDS (3 x 32KB), 512 thr = 8 waves, 1 barrier/subtile.
// R11 failed because STAGE_LOAD(t+2) and STAGE_WRITE(t+2) were in the SAME
// iteration -> write waited on just-issued fp32 loads (full HBM latency/iter).
// Fix: carry registers one iteration. At iter t:
//   ds_read slot t%3 + 32 MFMA
//   STAGE_WRITE(t+2, Rprev)   // loads issued at iter t-1 -> ~2000cyc distance
//   STAGE_LOAD(t+3, Rnext)    // for next iteration's write
//   lgkmcnt(0); s_barrier
// Ping-pong Ra/Rb via manual 2-body unroll (static indexing, rule #20).
// WAR: slot (t+2)%3 == slot (t-1)%3, whose reads finished before iter t began.

#define SBAR  __builtin_amdgcn_s_barrier()
#define LGKMB { asm volatile("s_waitcnt lgkmcnt(0)" ::: "memory"); }

DEVI short8 rdfrag(const char* unit, int row, int lg) {
  int L = row >> 1;
  int g = ((row & 1) << 2) + lg;
  return *(const short8*)(unit + L * 128 + ((g ^ (L & 7)) << 4));
}

__global__ __launch_bounds__(512, 2) void gemm_qkv8(
    const float* __restrict__ Adec, const float* __restrict__ Aenc,
    const float* __restrict__ Ww,
    const float* __restrict__ q_nw, const float* __restrict__ k_nw,
    unsigned short* __restrict__ q_bf, unsigned short* __restrict__ k_bf,
    unsigned short* __restrict__ v_t) {
  extern __shared__ char lds[];
  const int K = 2048, NST = 64;   // 64 subtiles of K=32

  // XCD swizzle over 192 = 8*24
  int flat = blockIdx.y * 8 + blockIdx.x;
  int swz = (flat & 7) * 24 + (flat >> 3);
  int bx = swz & 7, by = swz >> 3;

  const float* A;
  int bm0;
  if (by < 8) { A = Adec; bm0 = by * 256; }
  else        { A = Aenc; bm0 = (by - 8) * 256; }
  const float* Bp = Ww + (by < 8 ? 0 : (size_t)2048 * 2048);
  const int bn0 = bx * 256;

  const int tid = threadIdx.x, lane = tid & 63, wave = tid >> 6;
  const int lr = lane & 15, lg = lane >> 4;
  const int wr = wave >> 2, wc = wave & 3;   // 2M x 4N
  const int bq = (wc & 1) * 64;

  // staging source mapping: linear dest chunk tid*16 -> swizzled source row/col
  const int sB = tid * 16;
  const int sL = sB >> 7, sgp = (sB >> 4) & 7;
  const int sg = sgp ^ (sL & 7);
  const int st_row = sL * 2 + (sg >> 2);
  const int st_col = (sg & 3) * 8;
  const size_t a0off = (size_t)(bm0 + st_row) * K + st_col;       // fp32 elems
  const size_t a1off = a0off + (size_t)128 * K;
  const size_t b0off = (size_t)(bn0 + st_row) * K + st_col;
  const size_t b1off = b0off + (size_t)128 * K;

  f32x4 acc[8][4] = {};

#define MM(mq, aS, bS)                                                \
  {                                                                   \
    __builtin_amdgcn_s_setprio(1);                                    \
    _Pragma("unroll") for (int m = 0; m < 4; ++m)                     \
        _Pragma("unroll") for (int n = 0; n < 4; ++n)                 \
            acc[(mq)*4 + m][n] = __builtin_amdgcn_mfma_f32_16x16x32_bf16( \
                aS[m], bS[n], acc[(mq)*4 + m][n], 0, 0, 0);           \
    __builtin_amdgcn_s_setprio(0);                                    \
  }

#define STAGE_LOAD(t, R)                                              \
  {                                                                   \
    const size_t kc = (size_t)(t) * 32;                               \
    R[0] = *(const f32x4*)(A + a0off + kc);                           \
    R[1] = *(const f32x4*)(A + a0off + kc + 4);                       \
    R[2] = *(const f32x4*)(A + a1off + kc);                           \
    R[3] = *(const f32x4*)(A + a1off + kc + 4);                       \
    R[4] = *(const f32x4*)(Bp + b0off + kc);                          \
    R[5] = *(const f32x4*)(Bp + b0off + kc + 4);                      \
    R[6] = *(const f32x4*)(Bp + b1off + kc);                          \
    R[7] = *(const f32x4*)(Bp + b1off + kc + 4);                      \
  }
#define STAGE_WRITE(t, R)                                             \
  {                                                                   \
    char* base = lds + ((t) % 3) * 32768;                             \
    _Pragma("unroll") for (int u = 0; u < 4; ++u) {                   \
      unsigned w0 = cvtpk(R[u * 2][0], R[u * 2][1]);                  \
      unsigned w1 = cvtpk(R[u * 2][2], R[u * 2][3]);                  \
      unsigned w2 = cvtpk(R[u * 2 + 1][0], R[u * 2 + 1][1]);          \
      unsigned w3 = cvtpk(R[u * 2 + 1][2], R[u * 2 + 1][3]);          \
      uint4 pk = make_uint4(w0, w1, w2, w3);                          \
      *(uint4*)(base + u * 8192 + sB) = pk;                           \
    }                                                                 \
  }

#define BODY(t, Rp, Rn)                                               \
  {                                                                   \
    const char* ua = lds + ((t) % 3) * 32768 + wr * 8192;             \
    const char* ub = lds + ((t) % 3) * 32768 + 16384 + ((wc >> 1) << 13); \
    short8 a0[4], b0[4], a1[4];                                       \
    _Pragma("unroll") for (int m = 0; m < 4; ++m)                     \
        a0[m] = rdfrag(ua, m * 16 + lr, lg);                          \
    _Pragma("unroll") for (int n = 0; n < 4; ++n)                     \
        b0[n] = rdfrag(ub, bq + n * 16 + lr, lg);                     \
    MM(0, a0, b0);                                                    \
    _Pragma("unroll") for (int m = 0; m < 4; ++m)                     \
        a1[m] = rdfrag(ua, 64 + m * 16 + lr, lg);                     \
    MM(1, a1, b0);                                                    \
    if ((t) + 2 < NST) STAGE_WRITE((t) + 2, Rp);                      \
    if ((t) + 3 < NST) STAGE_LOAD((t) + 3, Rn);                       \
    LGKMB; SBAR;                                                      \
  }

  // ---- prologue: fill slots 0,1; issue loads for 2 ----
  f32x4 Ra[8], Rb[8];
  STAGE_LOAD(0, Ra); STAGE_WRITE(0, Ra);
  STAGE_LOAD(1, Ra); STAGE_WRITE(1, Ra);
  STAGE_LOAD(2, Ra);                        // carried into iter 0
  LGKMB; SBAR;

#pragma unroll 1
  for (int t = 0; t < NST; t += 2) {
    BODY(t, Ra, Rb);        // even: prev=Ra (data t+2), load t+3 into Rb
    BODY(t + 1, Rb, Ra);    // odd:  prev=Rb (data t+3), load t+4 into Ra
  }

  // ================= fused epilogue (unchanged) =================
  const int btype = (by < 8) ? 0 : (bx < 4 ? 1 : 2);  // 0=Q,1=K,2=V
  const int tokbase0 = (by < 8 ? by : by - 8) * 256;

  if (btype < 2) {
    float* Lf = (float*)lds;                 // [64][260] f32
    const float* wnorm = (btype == 0) ? q_nw : k_nw;
    const float fscale = (btype == 0) ? SCALING : 1.0f;
    unsigned short* dst = (btype == 0) ? q_bf : k_bf;
    const size_t LEN = (btype == 0) ? (size_t)QLEN : (size_t)KVLEN;
    const int dloc = lr * 8;
    float wv[8];
#pragma unroll
    for (int j = 0; j < 8; ++j) wv[j] = 1.0f + wnorm[dloc + j];

#pragma unroll
    for (int q = 0; q < 4; ++q) {
      SBAR;
      if (wr == (q >> 1)) {
        const int amb = (q & 1) * 4;
#pragma unroll
        for (int am2 = 0; am2 < 4; ++am2)
#pragma unroll
          for (int n = 0; n < 4; ++n)
#pragma unroll
            for (int r = 0; r < 4; ++r)
              Lf[(am2 * 16 + lg * 4 + r) * 260 + wc * 64 + n * 16 + lr] =
                  acc[amb + am2][n][r];
      }
      SBAR;
#pragma unroll
      for (int it = 0; it < 4; ++it) {
        int pair = it * 32 + wave * 4 + (lane >> 4);   // 0..127
        int row = pair >> 1, hh = pair & 1;
        const float* src = &Lf[row * 260 + hh * 128 + dloc];
        f32x4 x0 = *(const f32x4*)src;
        f32x4 x1 = *(const f32x4*)(src + 4);
        float ssq = x0[0]*x0[0] + x0[1]*x0[1] + x0[2]*x0[2] + x0[3]*x0[3] +
                    x1[0]*x1[0] + x1[1]*x1[1] + x1[2]*x1[2] + x1[3]*x1[3];
#pragma unroll
        for (int m = 8; m >= 1; m >>= 1) ssq += __shfl_xor(ssq, m);
        float sc = rsqrtf(ssq * (1.0f / 128.0f) + EPS) * fscale;
        short8 o;
        o[0] = (short)f2bf(x0[0] * sc * wv[0]); o[1] = (short)f2bf(x0[1] * sc * wv[1]);
        o[2] = (short)f2bf(x0[2] * sc * wv[2]); o[3] = (short)f2bf(x0[3] * sc * wv[3]);
        o[4] = (short)f2bf(x1[0] * sc * wv[4]); o[5] = (short)f2bf(x1[1] * sc * wv[5]);
        o[6] = (short)f2bf(x1[2] * sc * wv[6]); o[7] = (short)f2bf(x1[3] * sc * wv[7]);
        int tok = tokbase0 + q * 64 + row;
        int hd = 2 * bx + hh;
        *(short8*)&dst[((size_t)hd * LEN + tok) * 128 + dloc] = o;
      }
    }
  } else {
    float* Lv = (float*)lds;                 // [256 d][68] f32 (col-major quarter)
#pragma unroll
    for (int q = 0; q < 4; ++q) {
      SBAR;
      if (wr == (q >> 1)) {
        const int amb = (q & 1) * 4;
#pragma unroll
        for (int am2 = 0; am2 < 4; ++am2)
#pragma unroll
          for (int n = 0; n < 4; ++n)
            *(f32x4*)&Lv[(wc * 64 + n * 16 + lr) * 68 + am2 * 16 + lg * 4] =
                acc[amb + am2][n];
      }
      SBAR;
      int d = tid >> 1, th = tid & 1;        // d 0..255, token half
      const float* src = &Lv[d * 68 + th * 32];
      int kh = (bx - 4) * 2 + (d >> 7);
      int tok = tokbase0 + q * 64 + th * 32;
      unsigned short* vp = &v_t[((size_t)kh * 128 + (d & 127)) * KVLEN + tok];
#pragma unroll
      for (int j = 0; j < 4; ++j) {
        f32x4 v0 = *(const f32x4*)(src + j * 8);
        f32x4 v1 = *(const f32x4*)(src + j * 8 + 4);
        short8 o;
        o[0] = (short)f2bf(v0[0]); o[1] = (short)f2bf(v0[1]);
        o[2] = (short)f2bf(v0[2]); o[3] = (short)f2bf(v0[3]);
        o[4] = (short)f2bf(v1[0]); o[5] = (short)f2bf(v1[1]);
        o[6] = (short)f2bf(v1[2]); o[7] = (short)f2bf(v1[3]);
        *(short8*)(vp + j * 8) = o;
      }
    }
  }
#undef MM
#undef STAGE_LOAD
#undef STAGE_WRITE
#undef BODY
}

// ---------------- attention: K/V chunk double-buffer, 1 barrier/chunk ----------------
__global__ __launch_bounds__(256, 4) void attn_kernel(
    const unsigned short* __restrict__ qb,   // [16][2048][128]
    const unsigned short* __restrict__ kb,   // [8][4096][128]
    const unsigned short* __restrict__ vt,   // [8][128][4096]
    const int* __restrict__ seq_lens,
    float* __restrict__ out) {               // [2048][2048]
  __shared__ __align__(16) char smem[73728];

  const int h = blockIdx.y;
  const int t0 = blockIdx.x * 64;
  int req = 0, qs = 0;
#pragma unroll 1
  while (req < NREQ - 1 && qs + seq_lens[req] <= t0) { qs += seq_lens[req]; ++req; }
  const int slen = seq_lens[req];
  const int rows = min(64, qs + slen - t0);
  if (rows <= 0) return;
  const int qbase = t0;

  const int tid = threadIdx.x, lane = tid & 63, wave = tid >> 6;
  const int lr = lane & 15, lg = lane >> 4;
  const int m0w = wave * 16;
  const int kh = h >> 1;
  const int kv0 = req * ENCLEN;

#define STAGE_K(c, db)                                                        \
  _Pragma("unroll") for (int i = 0; i < 4; ++i) {                             \
    int idx = i * 256 + tid;                                                  \
    int row = idx >> 4, slot = idx & 15;                                      \
    g2l16(kb + ((size_t)kh * KVLEN + kv0 + (c) * 64 + row) * 128 +            \
              ((slot ^ (row & 15)) << 3),                                     \
          smem + (db) * 16384 + idx * 16);                                    \
  }
#define STAGE_V(c, db)                                                        \
  _Pragma("unroll") for (int i = 0; i < 4; ++i) {                             \
    int idx = i * 256 + tid;                                                  \
    int row = idx >> 3, slot = idx & 7;                                       \
    g2l16(vt + ((size_t)kh * 128 + row) * KVLEN + kv0 + (c) * 64 +            \
              ((slot ^ (row & 7)) << 3),                                      \
          smem + 32768 + (db) * 16384 + idx * 16);                            \
  }

  unsigned short* Ps = (unsigned short*)(smem + 65536);

  short8 a_q[4];
  {
    int qr = qbase + min(m0w + lr, rows - 1);
    const unsigned short* qp = qb + ((size_t)h * QLEN + qr) * 128 + lg * 8;
#pragma unroll
    for (int ks = 0; ks < 4; ++ks) a_q[ks] = *(const short8*)(qp + ks * 32);
  }

  f32x4 acc[8] = {};
  float mrow[4], lsum[4];
#pragma unroll
  for (int r = 0; r < 4; ++r) { mrow[r] = -1e30f; lsum[r] = 0.f; }

  STAGE_K(0, 0); STAGE_V(0, 0);

  int cb = 0;
#pragma unroll 1
  for (int c = 0; c < 8; ++c) {
    asm volatile("s_waitcnt vmcnt(0)" ::: "memory");
    __syncthreads();
    if (c < 7) { STAGE_K(c + 1, cb ^ 1); STAGE_V(c + 1, cb ^ 1); }
    const unsigned short* Kb = (const unsigned short*)(smem + cb * 16384);
    const unsigned short* Vb = (const unsigned short*)(smem + 32768 + cb * 16384);

    f32x4 s[4] = {};
#pragma unroll
    for (int ks = 0; ks < 4; ++ks) {
      short8 bk[4];
#pragma unroll
      for (int n = 0; n < 4; ++n) {
        int row = n * 16 + lr;
        bk[n] = *(const short8*)&Kb[row * 128 + (((ks * 4 + lg) ^ (row & 15)) << 3)];
      }
#pragma unroll
      for (int n = 0; n < 4; ++n)
        s[n] = __builtin_amdgcn_mfma_f32_16x16x32_bf16(a_q[ks], bk[n], s[n], 0, 0, 0);
    }

#pragma unroll
    for (int r = 0; r < 4; ++r) {
      float mx = fmaxf(fmaxf(s[0][r], s[1][r]), fmaxf(s[2][r], s[3][r]));
#pragma unroll
      for (int msk = 8; msk >= 1; msk >>= 1) mx = fmaxf(mx, __shfl_xor(mx, msk));
      float mnew = fmaxf(mrow[r], mx);
      float al = __expf(mrow[r] - mnew);
      mrow[r] = mnew;
      float rs = 0.f;
#pragma unroll
      for (int n = 0; n < 4; ++n) {
        float p = __expf(s[n][r] - mnew);
        s[n][r] = p;
        rs += p;
      }
#pragma unroll
      for (int msk = 8; msk >= 1; msk >>= 1) rs += __shfl_xor(rs, msk);
      lsum[r] = lsum[r] * al + rs;
#pragma unroll
      for (int n2 = 0; n2 < 8; ++n2) acc[n2][r] *= al;
    }

#pragma unroll
    for (int n = 0; n < 4; ++n)
#pragma unroll
      for (int r = 0; r < 4; ++r) {
        int row = m0w + lg * 4 + r;
        int col = n * 16 + lr;
        Ps[row * 64 + (col ^ ((row & 7) << 3))] = f2bf(s[n][r]);
      }
    asm volatile("s_waitcnt lgkmcnt(0)" ::: "memory");
    __builtin_amdgcn_sched_barrier(0);

#pragma unroll
    for (int ks = 0; ks < 2; ++ks) {
      int prow = m0w + lr;
      short8 pa = *(const short8*)&Ps[prow * 64 + (((ks * 4 + lg) ^ (prow & 7)) << 3)];
#pragma unroll
      for (int n2 = 0; n2 < 8; ++n2) {
        int row = n2 * 16 + lr;
        short8 bv = *(const short8*)&Vb[row * 64 + (((ks * 4 + lg) ^ (row & 7)) << 3)];
        acc[n2] = __builtin_amdgcn_mfma_f32_16x16x32_bf16(pa, bv, acc[n2], 0, 0, 0);
      }
    }
    cb ^= 1;
  }
  __syncthreads();

  float inv[4];
#pragma unroll
  for (int r = 0; r < 4; ++r) inv[r] = 1.0f / lsum[r];
#pragma unroll
  for (int n2 = 0; n2 < 8; ++n2)
#pragma unroll
    for (int r = 0; r < 4; ++r) acc[n2][r] *= inv[r];

  constexpr int OFS = 132;
  float* Of = (float*)smem;
#pragma unroll
  for (int n2 = 0; n2 < 8; ++n2)
#pragma unroll
    for (int r = 0; r < 4; ++r)
      Of[(m0w + lg * 4 + r) * OFS + n2 * 16 + lr] = acc[n2][r];
  __syncthreads();
#pragma unroll
  for (int p = 0; p < 8; ++p) {
    int idx = p * 256 + tid;
    int row = idx >> 5, c4 = (idx & 31) * 4;
    if (row < rows) {
      f32x4 v = *(const f32x4*)&Of[row * OFS + c4];
      *(f32x4*)&out[(size_t)(qbase + row) * 2048 + h * 128 + c4] = v;
    }
  }
#undef STAGE_K
#undef STAGE_V
}

// ---------------- launch ----------------
extern "C" void kernel_launch(void* const* d_in, const int* in_sizes, int n_in,
                              void* d_out, int out_size, void* d_ws, size_t ws_size,
                              hipStream_t stream) {
  const float* hidden = (const float*)d_in[0];
  const float* enc    = (const float*)d_in[1];
  const float* w_qkv  = (const float*)d_in[2];
  const float* q_nw   = (const float*)d_in[3];
  const float* k_nw   = (const float*)d_in[4];
  const int*   slens  = (const int*)d_in[5];
  float* out = (float*)d_out;

  char* ws = (char*)d_ws;
  unsigned short* q_bf = (unsigned short*)(ws + 0);           //  8.39 MB
  unsigned short* k_bf = (unsigned short*)(ws + 8388608);     //  8.39 MB
  unsigned short* v_t  = (unsigned short*)(ws + 16777216);    //  8.39 MB (ends 25.2MB)

  static bool attr_set = false;
  if (!attr_set) {
    hipFuncSetAttribute((const void*)gemm_qkv8,
                        hipFuncAttributeMaxDynamicSharedMemorySize, 131072);
    attr_set = true;
  }

  gemm_qkv8<<<dim3(8, 24), 512, 131072, stream>>>(hidden, enc, w_qkv, q_nw, k_nw,
                                                  q_bf, k_bf, v_t);

  attn_kernel<<<dim3(32, 16), 256, 0, stream>>>(q_bf, k_bf, v_t, slens, out);
}